// Round 4
// baseline (389.915 us; speedup 1.0000x reference)
//
#include <hip/hip_runtime.h>
#include <hip/hip_bf16.h>

#define HW 4096
#define CCH 64

typedef __attribute__((ext_vector_type(8))) short short8;
typedef __attribute__((ext_vector_type(4))) float f32x4;
typedef unsigned short ushort_t;

__device__ __forceinline__ unsigned short f2b(float f) {
  unsigned u = __float_as_uint(f);
  return (unsigned short)((u + 0x7fff + ((u >> 16) & 1)) >> 16);  // RNE
}

// ---------------- depthwise convs (3x3 pad1 + 5x5 pad2, reflect) ----------------
__global__ void __launch_bounds__(256) k_dwconv(
    const float* __restrict__ in, const float* __restrict__ w1, const float* __restrict__ b1,
    const float* __restrict__ w2, const float* __restrict__ b2,
    float* __restrict__ x, float* __restrict__ y) {
  __shared__ float sm[68 * 68];
  const int bc = blockIdx.x;           // b*64 + c
  const int c = bc & 63;
  const float* p = in + bc * HW;
  const int tid = threadIdx.x;
  for (int idx = tid; idx < 68 * 68; idx += 256) {
    int r = idx / 68 - 2, cc = idx % 68 - 2;
    r = r < 0 ? -r : (r > 63 ? 126 - r : r);
    cc = cc < 0 ? -cc : (cc > 63 ? 126 - cc : cc);
    sm[idx] = p[r * 64 + cc];
  }
  float w1r[9], w2r[25];
  for (int i = 0; i < 9; i++) w1r[i] = w1[c * 9 + i];
  for (int i = 0; i < 25; i++) w2r[i] = w2[c * 25 + i];
  const float bb1 = b1[c], bb2 = b2[c];
  __syncthreads();
  for (int k = 0; k < 16; k++) {
    int pix = tid + k * 256;
    int i = pix >> 6, j = pix & 63;
    float a1 = bb1, a2 = bb2;
    for (int u = 0; u < 3; u++)
      for (int v = 0; v < 3; v++)
        a1 += w1r[u * 3 + v] * sm[(i + 1 + u) * 68 + (j + 1 + v)];
    for (int u = 0; u < 5; u++)
      for (int v = 0; v < 5; v++)
        a2 += w2r[u * 5 + v] * sm[(i + u) * 68 + (j + v)];
    x[bc * HW + pix] = a1 > 0.f ? a1 : 0.01f * a1;
    y[bc * HW + pix] = a2 > 0.f ? a2 : 0.01f * a2;
  }
}

// ---------------- group norm, IN PLACE (16 groups of 4 channels) ----------------
__global__ void __launch_bounds__(256) k_gn(
    float* __restrict__ x, float* __restrict__ y,
    const float* __restrict__ gwA, const float* __restrict__ gbA,
    const float* __restrict__ gwB, const float* __restrict__ gbB) {
  const int id = blockIdx.x;          // 0..127: [tensor][b][g]
  const int t = id >> 6;
  const int b = (id >> 4) & 3;
  const int g = id & 15;
  float* buf = (t ? y : x) + b * (CCH * HW) + g * 4 * HW;
  const float* gw = t ? gwB : gwA;
  const float* gb = t ? gbB : gbA;
  const int tid = threadIdx.x;
  float s = 0.f, ss = 0.f;
  for (int i = tid; i < 4 * HW; i += 256) {
    float v = buf[i];
    s += v; ss += v * v;
  }
  for (int off = 1; off < 64; off <<= 1) {
    s += __shfl_xor(s, off);
    ss += __shfl_xor(ss, off);
  }
  __shared__ float rs[4], rss[4];
  const int w = tid >> 6;
  if ((tid & 63) == 0) { rs[w] = s; rss[w] = ss; }
  __syncthreads();
  s = rs[0] + rs[1] + rs[2] + rs[3];
  ss = rss[0] + rss[1] + rss[2] + rss[3];
  const float mu = s * (1.f / 16384.f);
  const float var = ss * (1.f / 16384.f) - mu * mu;
  const float rsig = rsqrtf(var + 1e-5f);
  for (int i = tid; i < 4 * HW; i += 256) {
    int ch = g * 4 + (i >> 12);
    buf[i] = (buf[i] - mu) * rsig * gw[ch] + gb[ch];
  }
}

// ---------------- qkv projection: writes Qt,Kt [h][pix][64] bf16 and V [h][64][pix] bf16 ----
__global__ void __launch_bounds__(256) k_qkv(
    const float* __restrict__ xA, const float* __restrict__ xB,
    const float* __restrict__ wA, const float* __restrict__ wB,
    ushort_t* __restrict__ Qt, ushort_t* __restrict__ Kt, ushort_t* __restrict__ Vv) {
  const int id = blockIdx.x * 256 + threadIdx.x;
  const int pg = id & 1023;
  const int chunk = (id >> 10) % 24;
  const int h = id / (1024 * 24);     // 0..7 = b*2+br
  const int b = h >> 1, br = h & 1;
  const float* X = (br ? xB : xA) + b * (CCH * HW);
  const float* W = br ? wB : wA;
  const int pix0 = pg * 4;
  const int r0 = chunk * 8;
  float acc[8][4];
  for (int r = 0; r < 8; r++) for (int p = 0; p < 4; p++) acc[r][p] = 0.f;
  for (int cc = 0; cc < 64; cc++) {
    const f32x4 xv = *(const f32x4*)(X + cc * HW + pix0);
    for (int r = 0; r < 8; r++) {
      float wv = W[(r0 + r) * 64 + cc];
      for (int p = 0; p < 4; p++) acc[r][p] += wv * xv[p];
    }
  }
  if (chunk < 16) {                    // Q or K rows -> transposed [pix][d]
    ushort_t* dst = chunk < 8 ? Qt : Kt;
    const int d0 = (chunk & 7) * 8;
    for (int p = 0; p < 4; p++) {
      short8 v;
      for (int r = 0; r < 8; r++) v[r] = (short)f2b(acc[r][p]);
      *(short8*)(dst + ((h * HW + pix0 + p) << 6) + d0) = v;
    }
  } else {                             // V rows -> natural [d][pix]
    const int d0 = (chunk - 16) * 8;
    for (int r = 0; r < 8; r++) {
      ushort_t tmp[4];
      for (int p = 0; p < 4; p++) tmp[p] = f2b(acc[r][p]);
      *(unsigned long long*)(Vv + (h * CCH + d0 + r) * HW + pix0) =
          *(const unsigned long long*)tmp;
    }
  }
}

// ---------------- flash cross-attention + fused out-proj + residual ----------------
// head h=(b,br): K/V from h, Q from (b,1-br). Per block: 64 queries, 4 waves x 16q.
__global__ void __launch_bounds__(256) k_attn(
    const ushort_t* __restrict__ Qt, const ushort_t* __restrict__ Kt,
    const ushort_t* __restrict__ Vv,
    const float* __restrict__ oAw, const float* __restrict__ oAb,
    const float* __restrict__ oBw, const float* __restrict__ oBb,
    const float* __restrict__ xA, const float* __restrict__ xB,
    float* __restrict__ out) {
  __shared__ char plds[8192];          // 2KB/wave: P^T staging [16q][64k] bf16, XOR-swizzled
  __shared__ float smO[64][64];        // attention output [ch][pix], 16KB
  const int h = blockIdx.x >> 6;
  const int qt = blockIdx.x & 63;
  const int b = h >> 1, br = h & 1;
  const int qh = b * 2 + (1 - br);
  const int lane = threadIdx.x & 63;
  const int wave = threadIdx.x >> 6;
  const int q = lane & 15, g = lane >> 4;
  const int qbase = qt * 64 + wave * 16;

  const ushort_t* Qp = Qt + ((qh * HW + qbase + q) << 6);
  const short8 qf0 = *(const short8*)(Qp + g * 8);        // B-frag: Q[d=g*8+j][q]
  const short8 qf1 = *(const short8*)(Qp + 32 + g * 8);

  const ushort_t* Kp = Kt + (h * HW << 6);
  const ushort_t* Vp = Vv + h * (CCH * HW);

  float m_run = -1e30f, l_run = 0.f;
  f32x4 o[4] = {};
  char* wp = plds + (wave << 11) + (q << 7);
  const int sw = (q & 7) << 4;

  for (int kt = 0; kt < 64; kt++) {
    const ushort_t* Kb = Kp + (kt * 64 << 6);
    short8 ka[4][2], va[4][2];
    for (int c = 0; c < 4; c++)
      for (int s = 0; s < 2; s++)
        ka[c][s] = *(const short8*)(Kb + ((c * 16 + q) << 6) + s * 32 + g * 8);
    for (int cd = 0; cd < 4; cd++)
      for (int s = 0; s < 2; s++)
        va[cd][s] = *(const short8*)(Vp + (cd * 16 + q) * HW + kt * 64 + s * 32 + g * 8);

    // S^T[k_local, q] = sum_d K[d,k] Q[d,q]   (swapped operands -> q is lane-local column)
    f32x4 sa[4];
    for (int c = 0; c < 4; c++) {
      f32x4 zz = {0.f, 0.f, 0.f, 0.f};
      zz = __builtin_amdgcn_mfma_f32_16x16x32_bf16(ka[c][0], qf0, zz, 0, 0, 0);
      sa[c] = __builtin_amdgcn_mfma_f32_16x16x32_bf16(ka[c][1], qf1, zz, 0, 0, 0);
    }
    const float sc = 0.125f * 1.44269504f;  // (1/sqrt(C)) * log2(e)
    float z[4][4];
    float mloc = -1e30f;
    for (int c = 0; c < 4; c++)
      for (int i = 0; i < 4; i++) {
        z[c][i] = sa[c][i] * sc;
        mloc = fmaxf(mloc, z[c][i]);
      }
    mloc = fmaxf(mloc, __shfl_xor(mloc, 16));
    mloc = fmaxf(mloc, __shfl_xor(mloc, 32));
    const float mnew = fmaxf(m_run, mloc);
    const float alpha = exp2f(m_run - mnew);
    float psum = 0.f;
    unsigned long long pk[4];
    for (int c = 0; c < 4; c++) {
      float p0 = exp2f(z[c][0] - mnew), p1 = exp2f(z[c][1] - mnew);
      float p2 = exp2f(z[c][2] - mnew), p3 = exp2f(z[c][3] - mnew);
      psum += p0 + p1 + p2 + p3;
      pk[c] = (unsigned long long)f2b(p0) | ((unsigned long long)f2b(p1) << 16) |
              ((unsigned long long)f2b(p2) << 32) | ((unsigned long long)f2b(p3) << 48);
    }
    psum += __shfl_xor(psum, 16);
    psum += __shfl_xor(psum, 32);
    m_run = mnew;
    l_run = l_run * alpha + psum;
    for (int cd = 0; cd < 4; cd++)
      for (int i = 0; i < 4; i++) o[cd][i] *= alpha;
    // stage P^T (keys c*16+4g+i at column q) into wave-local LDS, XOR-swizzled
    for (int c = 0; c < 4; c++)
      *(unsigned long long*)(wp + (((c << 5) | (g << 3)) ^ sw)) = pk[c];
    asm volatile("s_waitcnt lgkmcnt(0)" ::: "memory");
    __builtin_amdgcn_sched_barrier(0);
    const short8 pb0 = *(const short8*)(wp + ((g << 4) ^ sw));
    const short8 pb1 = *(const short8*)(wp + ((64 | (g << 4)) ^ sw));
    for (int cd = 0; cd < 4; cd++) {
      o[cd] = __builtin_amdgcn_mfma_f32_16x16x32_bf16(va[cd][0], pb0, o[cd], 0, 0, 0);
      o[cd] = __builtin_amdgcn_mfma_f32_16x16x32_bf16(va[cd][1], pb1, o[cd], 0, 0, 0);
    }
    asm volatile("s_waitcnt lgkmcnt(0)" ::: "memory");
    __builtin_amdgcn_sched_barrier(0);
  }

  // ---- fused epilogue: stage attn output to LDS, project, +bias +residual ----
  const float inv = 1.f / l_run;
  for (int cd = 0; cd < 4; cd++)
    for (int i = 0; i < 4; i++)
      smO[cd * 16 + g * 4 + i][wave * 16 + q] = o[cd][i] * inv;
  __syncthreads();

  const float* W    = br ? oBw : oAw;
  const float* bias = br ? oBb : oAb;
  const float* xR   = (br ? xB : xA) + b * (CCH * HW);
  const int pix = qt * 64 + lane;

  float acc[16];
  for (int oi = 0; oi < 16; oi++) acc[oi] = bias[wave * 16 + oi];
  for (int c4 = 0; c4 < 16; c4++) {
    f32x4 Lv = {smO[c4 * 4 + 0][lane], smO[c4 * 4 + 1][lane],
                smO[c4 * 4 + 2][lane], smO[c4 * 4 + 3][lane]};
    for (int oi = 0; oi < 16; oi++) {
      const f32x4 wv = *(const f32x4*)(W + (wave * 16 + oi) * 64 + c4 * 4);
      acc[oi] += wv[0] * Lv[0] + wv[1] * Lv[1] + wv[2] * Lv[2] + wv[3] * Lv[3];
    }
  }
  for (int oi = 0; oi < 16; oi++) {
    const int o_ch = wave * 16 + oi;
    out[(b * 128 + br * 64 + o_ch) * HW + pix] = acc[oi] + xR[o_ch * HW + pix];
  }
}

extern "C" void kernel_launch(void* const* d_in, const int* in_sizes, int n_in,
                              void* d_out, int out_size, void* d_ws, size_t ws_size,
                              hipStream_t stream) {
  const float* in   = (const float*)d_in[0];
  const float* dw1w = (const float*)d_in[1];
  const float* dw1b = (const float*)d_in[2];
  const float* dw2w = (const float*)d_in[3];
  const float* dw2b = (const float*)d_in[4];
  const float* gnAw = (const float*)d_in[5];
  const float* gnAb = (const float*)d_in[6];
  const float* gnBw = (const float*)d_in[7];
  const float* gnBb = (const float*)d_in[8];
  const float* qAw  = (const float*)d_in[9];
  const float* qBw  = (const float*)d_in[10];
  const float* oAw  = (const float*)d_in[11];
  const float* oAb  = (const float*)d_in[12];
  const float* oBw  = (const float*)d_in[13];
  const float* oBb  = (const float*)d_in[14];
  float* out = (float*)d_out;

  // compact workspace layout: 20 MB total
  char* ws = (char*)d_ws;
  float* xA = (float*)ws;                    // [4][64][4096] f32 (conv out, GN'd in place)
  float* xB = xA + 1048576;                  // [4][64][4096] f32
  ushort_t* Qt = (ushort_t*)(xB + 1048576);  // [8][4096][64] bf16
  ushort_t* Kt = Qt + 2097152;               // [8][4096][64] bf16
  ushort_t* Vv = Kt + 2097152;               // [8][64][4096] bf16

  k_dwconv<<<256, 256, 0, stream>>>(in, dw1w, dw1b, dw2w, dw2b, xA, xB);
  k_gn<<<128, 256, 0, stream>>>(xA, xB, gnAw, gnAb, gnBw, gnBb);
  k_qkv<<<768, 256, 0, stream>>>(xA, xB, qAw, qBw, Qt, Kt, Vv);
  k_attn<<<512, 256, 0, stream>>>(Qt, Kt, Vv, oAw, oAb, oBw, oBb, xA, xB, out);
}